// Round 9
// baseline (202.851 us; speedup 1.0000x reference)
//
#include <hip/hip_runtime.h>
#include <math.h>

#define T_NTIME  2048
#define T_NBATCH 128
#define T_INSIZE 512
#define T_SIZE   16
#define T_NROWS  (T_NTIME * T_NBATCH)
#define MAT_STRIDE 24

typedef __attribute__((ext_vector_type(8))) short s8v;    // 8 bf16 (4 VGPR)
typedef __attribute__((ext_vector_type(4))) float f32x4;  // MFMA acc
typedef unsigned short ushortx;
typedef unsigned int uintx;

__device__ __forceinline__ float sp_f(float v) {
  return fmaxf(v, 0.0f) + log1pf(__expf(-fabsf(v)));
}
__device__ __forceinline__ float tanh5_f(float v) {
  float a = fabsf(v);
  float e = __expf(-2.0f * a);
  float t = (1.0f - e) / (1.0f + e);
  return copysignf(5.0f * t, v);
}
__device__ __forceinline__ float lae_f(float a, float c) {
  float m = fmaxf(a, c);
  return m + log1pf(__expf(-fabsf(a - c)));
}
// round-to-nearest-even f32 -> bf16 bits, and bf16 of the residual
__device__ __forceinline__ void bf16_split(float f, ushortx& hi, ushortx& lo) {
  unsigned u = __float_as_uint(f);
  unsigned hb = (u + 0x7fffu + ((u >> 16) & 1u)) >> 16;
  float hf = __uint_as_float(hb << 16);
  float l = f - hf;
  unsigned ul = __float_as_uint(l);
  unsigned lb = (ul + 0x7fffu + ((ul >> 16) & 1u)) >> 16;
  hi = (ushortx)hb;
  lo = (ushortx)lb;
}
__device__ __forceinline__ uintx packw(float f) {
  ushortx h, l;
  bf16_split(f, h, l);
  return ((uintx)h << 16) | (uintx)l;
}

// ---------- K1: barrier-free wave-autonomous MFMA GEMM ----------
// Each wave owns 16-row output tiles (full K=512): no cross-wave reduce, no
// per-tile __syncthreads. K streamed in BK=64 steps through wave-private
// double-buffered LDS (XOR-swizzled granules). W cached in LDS as packed
// (bf16_hi<<16)|bf16_lo (one barrier at init only). 3-chain hi/lo MFMA.
__global__ __launch_bounds__(256, 2)
void k1_wavepipe(const float* __restrict__ x, const float* __restrict__ W,
                 const float* __restrict__ bias, float* __restrict__ out) {
  __shared__ uintx wp[16][512];        // 32 KB  [s][ ((k>>2)^(s&7))*4 + (k&3) ]
  __shared__ float xb[4][2][16][64];   // 32 KB  granule slot g^(row&7)
  const int tid = threadIdx.x;

  // --- one-time W pack (coalesced read, swizzled LDS write) ---
  {
    const float4* src = (const float4*)W;
#pragma unroll
    for (int k = 0; k < 8; ++k) {
      const int f4 = tid + k * 256;        // float4 index in W
      const float4 v = src[f4];
      const int s = f4 >> 7;               // row (512 floats = 128 float4)
      const int g = f4 & 127;              // granule (4 k's)
      const int slot = g ^ (s & 7);
      uint4 p;
      p.x = packw(v.x); p.y = packw(v.y); p.z = packw(v.z); p.w = packw(v.w);
      *(uint4*)&wp[s][slot * 4] = p;
    }
  }
  __syncthreads();

  const int l = tid & 63;
  const int w = tid >> 6;
  const int lr = l & 15;        // MFMA fragment row (x-row / out col=lane&15)
  const int lk = (l >> 4) & 3;  // k-subgroup
  const int srow = l >> 2;      // staging row 0..15
  const int sq = l & 3;         // staging quad 0..3
  const int r7 = lr & 7;

  const long gw = (long)blockIdx.x * 4 + w;
  const long rowbase = gw * 128;                 // 8 tiles x 16 rows per wave
  const float* __restrict__ xbase = x + rowbase * T_INSIZE;
  const float* __restrict__ sb = xbase + srow * T_INSIZE + sq * 4;
  float (*myx)[16][64] = xb[w];
  const float4 bv = *(const float4*)(bias + lk * 4);

  // prologue: stage flat-step 0 (tile 0, ks 0)
#pragma unroll
  for (int j = 0; j < 4; ++j) {
    const float4 v = *(const float4*)(sb + j * 16);
    myx[0][srow][((sq + 4 * j) ^ (srow & 7)) * 4 + 0] = v.x;
    *(float4*)&myx[0][srow][((sq + 4 * j) ^ (srow & 7)) * 4] = v;
  }

  f32x4 acc = {0.f, 0.f, 0.f, 0.f};
#pragma unroll 1
  for (int m = 0; m < 64; ++m) {          // flat step: tile = m>>3, ks = m&7
    const int ks = m & 7;
    // issue next-step global loads (fly under this step's compute)
    float4 st0, st1, st2, st3;
    const int mn = m + 1;
    if (mn < 64) {
      const float* srcp = sb + (long)(mn >> 3) * (16 * T_INSIZE) + (mn & 7) * 64;
      st0 = *(const float4*)(srcp);
      st1 = *(const float4*)(srcp + 16);
      st2 = *(const float4*)(srcp + 32);
      st3 = *(const float4*)(srcp + 48);
    }

    // compute current step from myx[m&1]
    const float* bufr = &myx[m & 1][0][0];
#pragma unroll
    for (int chain = 0; chain < 2; ++chain) {
      const int gA = (ks << 4) + (chain << 3) + (lk << 1);  // W granule
      const uint4 ua = *(const uint4*)&wp[lr][(gA ^ r7) * 4];
      const uint4 ub = *(const uint4*)&wp[lr][((gA + 1) ^ r7) * 4];
      s8v ah, al;
      ah[0] = (short)(ua.x >> 16); al[0] = (short)(ua.x & 0xffff);
      ah[1] = (short)(ua.y >> 16); al[1] = (short)(ua.y & 0xffff);
      ah[2] = (short)(ua.z >> 16); al[2] = (short)(ua.z & 0xffff);
      ah[3] = (short)(ua.w >> 16); al[3] = (short)(ua.w & 0xffff);
      ah[4] = (short)(ub.x >> 16); al[4] = (short)(ub.x & 0xffff);
      ah[5] = (short)(ub.y >> 16); al[5] = (short)(ub.y & 0xffff);
      ah[6] = (short)(ub.z >> 16); al[6] = (short)(ub.z & 0xffff);
      ah[7] = (short)(ub.w >> 16); al[7] = (short)(ub.w & 0xffff);

      const int gB = (chain << 3) + (lk << 1);              // x granule
      const float4 b0 = *(const float4*)&bufr[lr * 64 + ((gB ^ r7) << 2)];
      const float4 b1 = *(const float4*)&bufr[lr * 64 + (((gB + 1) ^ r7) << 2)];
      const float f[8] = {b0.x, b0.y, b0.z, b0.w, b1.x, b1.y, b1.z, b1.w};
      s8v bh, bl;
#pragma unroll
      for (int j = 0; j < 8; ++j) {
        ushortx h, lo2; bf16_split(f[j], h, lo2);
        bh[j] = (short)h; bl[j] = (short)lo2;
      }
      acc = __builtin_amdgcn_mfma_f32_16x16x32_bf16(ah, bh, acc, 0, 0, 0);
      acc = __builtin_amdgcn_mfma_f32_16x16x32_bf16(ah, bl, acc, 0, 0, 0);
      acc = __builtin_amdgcn_mfma_f32_16x16x32_bf16(al, bh, acc, 0, 0, 0);
    }

    // write staged regs into the other wave-private buffer (no barrier)
    if (mn < 64) {
      float (*dst)[64] = myx[mn & 1];
#pragma unroll
      for (int j = 0; j < 4; ++j) {
        const float4 v = (j == 0) ? st0 : (j == 1) ? st1 : (j == 2) ? st2 : st3;
        *(float4*)&dst[srow][((sq + 4 * j) ^ (srow & 7)) * 4] = v;
      }
    }

    // tile epilogue: every wave finalizes its own rows
    if (ks == 7) {
      const int tile = m >> 3;
      const float y0 = acc[0] + bv.x;
      const float y1 = acc[1] + bv.y;
      const float y2 = acc[2] + bv.z;
      const float y3 = acc[3] + bv.w;
      float4 o;
      if (lk == 0) {
        o.x = 1.0f + sp_f(y0); o.y = 1.0f + sp_f(y1);
        o.z = 1.0f + sp_f(y2); o.w = 1.0f + sp_f(y3);
      } else if (lk == 1) {
        o.x = 0.1f + sp_f(y0); o.y = 0.1f + sp_f(y1);
        o.z = 0.1f + sp_f(y2); o.w = 0.1f + sp_f(y3);
      } else {
        o.x = tanh5_f(y0); o.y = tanh5_f(y1);
        o.z = tanh5_f(y2); o.w = tanh5_f(y3);
      }
      *(float4*)(out + (rowbase + (long)tile * 16 + lr) * T_SIZE + lk * 4) = o;
      acc[0] = 0.f; acc[1] = 0.f; acc[2] = 0.f; acc[3] = 0.f;
    }
  }
}

// ---------- K2a: per-(b, chunk, basis-col) chunk transfer-matrix columns ----------
__global__ void k_scan_chunks(const float* __restrict__ out, float* __restrict__ mats,
                              int nchunks) {
  const int gtid = blockIdx.x * blockDim.x + threadIdx.x;
  const int colslot = gtid & 7;
  const int b = (gtid >> 3) & (T_NBATCH - 1);
  const int chunk = gtid >> 10;
  if (chunk >= nchunks) return;
  if (colslot >= 5) return;

  const int steps = T_NTIME / nchunks;
  const int t0 = chunk * steps;
  const float NEG = -1e30f;
  float f0 = (colslot == 0) ? 0.0f : NEG;
  float f1 = (colslot == 1) ? 0.0f : NEG;
  float f2 = (colslot == 2) ? 0.0f : NEG;
  float f3 = (colslot == 3) ? 0.0f : NEG;
  const float t4 = (colslot == 4) ? 0.0f : NEG;

  const long stride = T_NBATCH * T_SIZE;
  const float* p = out + ((long)t0 * T_NBATCH + b) * T_SIZE + 8;
  float4 mv = *(const float4*)(p);
  float4 st = *(const float4*)(p + 4);
  for (int s = 0; s < steps; ++s) {
    const float* pn = (s + 1 < steps) ? p + stride : p;
    const float4 mvn = *(const float4*)(pn);
    const float4 stn = *(const float4*)(pn + 4);

    float m, ss0, ss1, ss2, ss3;
    m = fmaxf(fmaxf(f1, f2), fmaxf(f3, t4));
    ss0 = m + __logf(__expf(f1 - m) + __expf(f2 - m) + __expf(f3 - m) + __expf(t4 - m));
    m = fmaxf(fmaxf(f0, f2), fmaxf(f3, t4));
    ss1 = m + __logf(__expf(f0 - m) + __expf(f2 - m) + __expf(f3 - m) + __expf(t4 - m));
    m = fmaxf(fmaxf(f0, f1), fmaxf(f3, t4));
    ss2 = m + __logf(__expf(f0 - m) + __expf(f1 - m) + __expf(f3 - m) + __expf(t4 - m));
    m = fmaxf(fmaxf(f0, f1), fmaxf(f2, t4));
    ss3 = m + __logf(__expf(f0 - m) + __expf(f1 - m) + __expf(f2 - m) + __expf(t4 - m));

    const float n0 = lae_f(f0 + st.x, ss0 + mv.x);
    const float n1 = lae_f(f1 + st.y, ss1 + mv.y);
    const float n2 = lae_f(f2 + st.z, ss2 + mv.z);
    const float n3 = lae_f(f3 + st.w, ss3 + mv.w);
    f0 = n0; f1 = n1; f2 = n2; f3 = n3;
    mv = mvn; st = stn; p = pn;
  }
  float* d = mats + ((long)chunk * T_NBATCH + b) * MAT_STRIDE + colslot * 4;
  float4 o; o.x = f0; o.y = f1; o.z = f2; o.w = f3;
  *(float4*)d = o;
}

// ---------- K2b: serial combine of chunk matrices per batch; logZ/T out ----------
__global__ void k_combine(const float* __restrict__ mats, float* __restrict__ logz,
                          int nchunks) {
  const int tid = threadIdx.x;
  const int i = tid & 3;
  const int b = tid >> 2;
  if (b >= T_NBATCH) return;
  float v = 0.0f;

  const float* Tb = mats + (long)b * MAT_STRIDE;
  const long cstride = (long)T_NBATCH * MAT_STRIDE;
  float q0 = Tb[i * 4 + i];
  float q1 = Tb[((i ^ 1) * 4) + i];
  float q2 = Tb[((i ^ 2) * 4) + i];
  float q3 = Tb[((i ^ 3) * 4) + i];
  float q4 = Tb[16 + i];
  for (int c = 0; c < nchunks; ++c) {
    const float* Tn = Tb + cstride;
    float n0 = 0, n1 = 0, n2 = 0, n3 = 0, n4 = 0;
    if (c + 1 < nchunks) {
      n0 = Tn[i * 4 + i];
      n1 = Tn[((i ^ 1) * 4) + i];
      n2 = Tn[((i ^ 2) * 4) + i];
      n3 = Tn[((i ^ 3) * 4) + i];
      n4 = Tn[16 + i];
    }
    const float vx1 = __shfl_xor(v, 1);
    const float vx2 = __shfl_xor(v, 2);
    const float vx3 = __shfl_xor(v, 3);
    const float a0 = q0 + v;
    const float a1 = q1 + vx1;
    const float a2 = q2 + vx2;
    const float a3 = q3 + vx3;
    const float a4 = q4;
    float m = fmaxf(fmaxf(a0, a1), fmaxf(fmaxf(a2, a3), a4));
    v = m + __logf(__expf(a0 - m) + __expf(a1 - m) + __expf(a2 - m) +
                   __expf(a3 - m) + __expf(a4 - m));
    q0 = n0; q1 = n1; q2 = n2; q3 = n3; q4 = n4;
    Tb = Tn;
  }
  float m1 = fmaxf(v, __shfl_xor(v, 1));
  m1 = fmaxf(m1, __shfl_xor(m1, 2));
  float e = __expf(v - m1);
  e += __shfl_xor(e, 1);
  e += __shfl_xor(e, 2);
  const float lz = m1 + __logf(e);
  if (i == 0) logz[b] = lz * (1.0f / (float)T_NTIME);
}

// ---------- K3: out[t][b][8..15] -= logZ[b]/T ----------
__global__ void k_sub(float* __restrict__ out, const float* __restrict__ logz) {
  const long n = (long)blockIdx.x * blockDim.x + threadIdx.x;
  if (n >= (long)T_NROWS * 2) return;
  const long tb = n >> 1;
  const int b = (int)(tb & (T_NBATCH - 1));
  const float lz = logz[b];
  float4* p = (float4*)(out + tb * T_SIZE + 8 + (n & 1) * 4);
  float4 v = *p;
  v.x -= lz; v.y -= lz; v.z -= lz; v.w -= lz;
  *p = v;
}

extern "C" void kernel_launch(void* const* d_in, const int* in_sizes, int n_in,
                              void* d_out, int out_size, void* d_ws, size_t ws_size,
                              hipStream_t stream) {
  const float* x    = (const float*)d_in[0];
  const float* W    = (const float*)d_in[1];
  const float* bias = (const float*)d_in[2];
  float* out = (float*)d_out;
  float* ws  = (float*)d_ws;

  int C = 64;
  while (C > 1 && (size_t)((long)C * T_NBATCH * MAT_STRIDE + T_NBATCH) * 4 > ws_size) C >>= 1;
  float* mats = ws;
  float* logz = ws + (long)C * T_NBATCH * MAT_STRIDE;

  k1_wavepipe<<<512, 256, 0, stream>>>(x, W, bias, out);

  const int thr2 = C * T_NBATCH * 8;
  k_scan_chunks<<<thr2 / 256, 256, 0, stream>>>(out, mats, C);
  k_combine<<<1, 512, 0, stream>>>(mats, logz, C);
  k_sub<<<(T_NROWS * 2) / 256, 256, 0, stream>>>(out, logz);
}